// Round 2
// baseline (934.878 us; speedup 1.0000x reference)
//
#include <hip/hip_runtime.h>
#include <math.h>

#define N_ATOMS 2048
#define NM      512
#define KHALF   9040          // half k-grid (k=0 excluded; pairs f <-> 18080-f folded into wk^2=2*kfac)
#define KPAD    9216          // padded, wk=0 on pads
#define TWO_PI  6.2831853071795864769f
#define SIGMA   0.5540037f
#define FOUR_PI 12.566370614359172954f

__device__ inline void inv3x3(const float* __restrict__ c, float inv[3][3], float& det) {
    float a00=c[0],a01=c[1],a02=c[2],a10=c[3],a11=c[4],a12=c[5],a20=c[6],a21=c[7],a22=c[8];
    float c00 =  a11*a22 - a12*a21;
    float c01 = -(a10*a22 - a12*a20);
    float c02 =  a10*a21 - a11*a20;
    det = a00*c00 + a01*c01 + a02*c02;
    float id = 1.0f/det;
    inv[0][0] = c00*id;
    inv[0][1] = -(a01*a22 - a02*a21)*id;
    inv[0][2] =  (a01*a12 - a02*a11)*id;
    inv[1][0] = c01*id;
    inv[1][1] =  (a00*a22 - a02*a20)*id;
    inv[1][2] = -(a00*a12 - a02*a10)*id;
    inv[2][0] = c02*id;
    inv[2][1] = -(a00*a21 - a01*a20)*id;
    inv[2][2] =  (a00*a11 - a01*a10)*id;
}

__global__ void k_setup(const float* __restrict__ cell, float4* __restrict__ kdata) {
    int t = blockIdx.x*256 + threadIdx.x;
    if (t >= KPAD) return;
    float gx=0.f, gy=0.f, gz=0.f, wk=0.f;
    if (t < KHALF) {
        int iz = t % 41; int rem = t / 41; int iy = rem % 21; int ix = rem / 21;
        gx = (float)(ix - 10); gy = (float)(iy - 10); gz = (float)(iz - 20);
        float inv[3][3], det;
        inv3x3(cell, inv, det);
        float kx = TWO_PI*(gx*inv[0][0] + gy*inv[0][1] + gz*inv[0][2]);
        float ky = TWO_PI*(gx*inv[1][0] + gy*inv[1][1] + gz*inv[1][2]);
        float kz = TWO_PI*(gx*inv[2][0] + gy*inv[2][1] + gz*inv[2][2]);
        float k2 = kx*kx + ky*ky + kz*kz;
        float kfac = __expf(-0.5f*SIGMA*SIGMA*k2) / k2;
        wk = sqrtf(2.0f*kfac);
    }
    kdata[t] = make_float4(gx, gy, gz, wk);
}

__global__ void atoms_prep(const float* __restrict__ pos, const float* __restrict__ q,
                           const float* __restrict__ cell, float4* __restrict__ uq,
                           float* __restrict__ out) {
    int i = blockIdx.x*256 + threadIdx.x;
    if (i < N_ATOMS) {
        float inv[3][3], det;
        inv3x3(cell, inv, det);
        float x = pos[3*i], y = pos[3*i+1], z = pos[3*i+2];
        float u = x*inv[0][0] + y*inv[1][0] + z*inv[2][0];
        float v = x*inv[0][1] + y*inv[1][1] + z*inv[2][1];
        float w = x*inv[0][2] + y*inv[1][2] + z*inv[2][2];
        float qi = q[i];
        uq[i] = make_float4(u, v, w, qi);
        if (i >= NM) out[i] = qi;
        if (i == 0) { out[N_ATOMS] = 0.f; out[N_ATOMS+1] = 0.f; }
    }
}

__global__ void structf(const float4* __restrict__ kdata, const float4* __restrict__ uq,
                        float* __restrict__ Scw, float* __restrict__ Ssw) {
    int t = blockIdx.x*256 + threadIdx.x;
    if (t >= KPAD) return;
    float4 kd = kdata[t];
    float sc = 0.f, ss = 0.f;
    for (int j = NM; j < N_ATOMS; ++j) {
        float4 a = uq[j];
        float ph = TWO_PI*(kd.x*a.x + kd.y*a.y + kd.z*a.z);
        float s, c;
        __sincosf(ph, &s, &c);
        sc += a.w * c;
        ss += a.w * s;
    }
    float kfac2 = kd.w * kd.w;
    Scw[t] = kfac2 * sc;
    Ssw[t] = kfac2 * ss;
}

__global__ void __launch_bounds__(512) field_metal(const float4* __restrict__ kdata,
        const float4* __restrict__ uq, const float* __restrict__ Scw,
        const float* __restrict__ Ssw, const float* __restrict__ cell,
        float* __restrict__ Bvec) {
    int gtid = blockIdx.x*512 + threadIdx.x;
    int atom = gtid >> 6;
    int lane = threadIdx.x & 63;
    float4 a = uq[atom];
    float acc = 0.f;
    for (int k = lane; k < KPAD; k += 64) {
        float4 kd = kdata[k];
        float ph = TWO_PI*(kd.x*a.x + kd.y*a.y + kd.z*a.z);
        float s, c;
        __sincosf(ph, &s, &c);
        acc += c*Scw[k] + s*Ssw[k];
    }
    #pragma unroll
    for (int off = 32; off; off >>= 1) acc += __shfl_down(acc, off);
    if (lane == 0) {
        float inv[3][3], det;
        inv3x3(cell, inv, det);
        float V = fabsf(det);
        Bvec[atom] = -(FOUR_PI / V) * acc;
    }
}

// Split-K SYRK over lower-triangle 128x128 tiles; phases recomputed into LDS per chunk.
__global__ void __launch_bounds__(256, 2) syrk_tiles(const float4* __restrict__ kdata,
        const float4* __restrict__ uq, float* __restrict__ partial, int KS, int KSL) {
    int s = blockIdx.x % KS;
    int t = blockIdx.x / KS;
    int rt = 0;
    while ((rt+1)*(rt+2)/2 <= t) ++rt;
    int ct = t - rt*(rt+1)/2;
    const int row0 = rt << 7, c0 = ct << 7;
    __shared__ float crT[32][128];
    __shared__ float srT[32][128];
    __shared__ float ccT[32][128];
    __shared__ float scT[32][128];
    const int tid = threadIdx.x;
    const int i0 = (tid & 15) << 3;
    const int j0 = (tid >> 4) << 3;
    float acc[8][8];
    #pragma unroll
    for (int i = 0; i < 8; ++i)
        #pragma unroll
        for (int j = 0; j < 8; ++j) acc[i][j] = 0.f;
    const int k0 = s * KSL;
    const int nch = KSL >> 5;
    for (int ch = 0; ch < nch; ++ch) {
        int kc = k0 + (ch << 5);
        __syncthreads();
        #pragma unroll
        for (int w = 0; w < 16; ++w) {
            int job = tid + (w << 8);
            int kk = job >> 7, a = job & 127;
            float4 kd = kdata[kc + kk];
            float4 at = uq[row0 + a];
            float ph = TWO_PI*(kd.x*at.x + kd.y*at.y + kd.z*at.z);
            float sn, cs;
            __sincosf(ph, &sn, &cs);
            crT[kk][a] = kd.w * cs;
            srT[kk][a] = kd.w * sn;
        }
        #pragma unroll
        for (int w = 0; w < 16; ++w) {
            int job = tid + (w << 8);
            int kk = job >> 7, a = job & 127;
            float4 kd = kdata[kc + kk];
            float4 at = uq[c0 + a];
            float ph = TWO_PI*(kd.x*at.x + kd.y*at.y + kd.z*at.z);
            float sn, cs;
            __sincosf(ph, &sn, &cs);
            ccT[kk][a] = kd.w * cs;
            scT[kk][a] = kd.w * sn;
        }
        __syncthreads();
        #pragma unroll 4
        for (int kk = 0; kk < 32; ++kk) {
            float cr[8], sr[8], cc[8], sv[8];
            *(float4*)&cr[0] = *(const float4*)&crT[kk][i0];
            *(float4*)&cr[4] = *(const float4*)&crT[kk][i0+4];
            *(float4*)&sr[0] = *(const float4*)&srT[kk][i0];
            *(float4*)&sr[4] = *(const float4*)&srT[kk][i0+4];
            *(float4*)&cc[0] = *(const float4*)&ccT[kk][j0];
            *(float4*)&cc[4] = *(const float4*)&ccT[kk][j0+4];
            *(float4*)&sv[0] = *(const float4*)&scT[kk][j0];
            *(float4*)&sv[4] = *(const float4*)&scT[kk][j0+4];
            #pragma unroll
            for (int i = 0; i < 8; ++i)
                #pragma unroll
                for (int j = 0; j < 8; ++j)
                    acc[i][j] += cr[i]*cc[j] + sr[i]*sv[j];
        }
    }
    float* P = partial + ((size_t)(t*KS + s) << 14);
    #pragma unroll
    for (int i = 0; i < 8; ++i) {
        *(float4*)&P[(i0+i)*128 + j0]     = make_float4(acc[i][0], acc[i][1], acc[i][2], acc[i][3]);
        *(float4*)&P[(i0+i)*128 + j0 + 4] = make_float4(acc[i][4], acc[i][5], acc[i][6], acc[i][7]);
    }
}

__global__ void reduceA(const float* __restrict__ partial, float* __restrict__ Amat,
                        const float* __restrict__ cell, int KS) {
    int idx = blockIdx.x*256 + threadIdx.x;
    if (idx >= 512*512) return;
    int i = idx >> 9, j = idx & 511;
    if (i < j) return;
    int rt = i >> 7, ct = j >> 7;
    int t = rt*(rt+1)/2 + ct;
    const float* p = partial + ((size_t)(t*KS) << 14) + ((i & 127) << 7) + (j & 127);
    float sum = 0.f;
    for (int s = 0; s < KS; ++s) sum += p[(size_t)s << 14];
    float inv[3][3], det;
    inv3x3(cell, inv, det);
    float v = (FOUR_PI / fabsf(det)) * sum;
    Amat[(size_t)i*512 + j] = v;
    Amat[(size_t)j*512 + i] = v;
}

// Cholesky panel (64 cols), rows-in-registers. Launched with block = 512-64p threads.
__global__ void __launch_bounds__(512) chol_panel(float* __restrict__ Amat, int p) {
    const int col0 = 64*p;
    const int tid = threadIdx.x;
    __shared__ float pivd[8];
    __shared__ float colsm[8][8];
    __shared__ float LcB[64][8];
    float row[64];
    const int grow = col0 + tid;
    {
        const float* ar = Amat + (size_t)grow*512 + col0;
        #pragma unroll
        for (int c = 0; c < 64; c += 4) *(float4*)&row[c] = *(const float4*)&ar[c];
    }
    #pragma unroll
    for (int jb = 0; jb < 64; jb += 8) {
        #pragma unroll
        for (int jj = 0; jj < 8; ++jj) {
            const int j = jb + jj;
            if (tid == j) pivd[jj] = row[j];
            else if (tid > j && tid < jb+8) colsm[jj][tid - jb] = row[j];
            __syncthreads();
            if (tid > j) {
                float inv = 1.0f / sqrtf(pivd[jj]);
                row[j] *= inv;
                #pragma unroll
                for (int c = jj+1; c < 8; ++c)
                    row[jb+c] -= row[j] * (colsm[jj][c] * inv);
            } else if (tid == j) {
                row[j] = sqrtf(pivd[jj]);
            }
        }
        if (tid >= jb+8 && tid < 64) {
            #pragma unroll
            for (int jj = 0; jj < 8; ++jj) LcB[tid][jj] = row[jb+jj];
        }
        __syncthreads();
        if (tid >= jb+8) {
            #pragma unroll
            for (int c = jb+8; c < 64; ++c) {
                float4 l0 = *(const float4*)&LcB[c][0];
                float4 l1 = *(const float4*)&LcB[c][4];
                row[c] -= row[jb+0]*l0.x + row[jb+1]*l0.y + row[jb+2]*l0.z + row[jb+3]*l0.w
                        + row[jb+4]*l1.x + row[jb+5]*l1.y + row[jb+6]*l1.z + row[jb+7]*l1.w;
            }
        }
        __syncthreads();
    }
    {
        float* ar = Amat + (size_t)grow*512 + col0;
        #pragma unroll
        for (int c = 0; c < 64; c += 4) *(float4*)&ar[c] = *(const float4*)&row[c];
    }
}

__global__ void __launch_bounds__(256) chol_trail(float* __restrict__ Amat, int p) {
    const int col0 = p*64, base = col0 + 64;
    int t = blockIdx.x;
    int rt = 0;
    while ((rt+1)*(rt+2)/2 <= t) ++rt;
    int ct = t - rt*(rt+1)/2;
    const int row0 = base + rt*64, c0 = base + ct*64;
    __shared__ float LrT[64][68];
    __shared__ float LcT[64][68];
    const int tid = threadIdx.x;
    for (int idx = tid; idx < 4096; idx += 256) {
        int k = idx & 63, r = idx >> 6;
        LrT[k][r] = Amat[(size_t)(row0+r)*512 + col0 + k];
        LcT[k][r] = Amat[(size_t)(c0 +r)*512 + col0 + k];
    }
    __syncthreads();
    const int i0 = (tid & 15)*4, j0 = (tid >> 4)*4;
    float acc[4][4];
    #pragma unroll
    for (int i = 0; i < 4; ++i)
        #pragma unroll
        for (int j = 0; j < 4; ++j) acc[i][j] = 0.f;
    #pragma unroll 8
    for (int k = 0; k < 64; ++k) {
        float a[4], b[4];
        *(float4*)a = *(const float4*)&LrT[k][i0];
        *(float4*)b = *(const float4*)&LcT[k][j0];
        #pragma unroll
        for (int i = 0; i < 4; ++i)
            #pragma unroll
            for (int j = 0; j < 4; ++j) acc[i][j] += a[i]*b[j];
    }
    #pragma unroll
    for (int i = 0; i < 4; ++i) {
        float* ap = &Amat[(size_t)(row0+i0+i)*512 + c0 + j0];
        float4 v = *(float4*)ap;
        v.x -= acc[i][0]; v.y -= acc[i][1]; v.z -= acc[i][2]; v.w -= acc[i][3];
        *(float4*)ap = v;
    }
}

// Invert the 8 diagonal 64x64 blocks of L (one block each, single wave, column-parallel).
__global__ void __launch_bounds__(64) inv_diag(const float* __restrict__ Amat,
                                               float* __restrict__ W) {
    int b = blockIdx.x;
    int c = threadIdx.x;
    __shared__ float D[64][65];
    __shared__ float T[64][65];
    for (int idx = c; idx < 4096; idx += 64) {
        int r = idx >> 6, j = idx & 63;
        D[r][j] = Amat[(size_t)(b*64+r)*512 + b*64 + j];
    }
    __syncthreads();
    for (int r = 0; r < 64; ++r) {
        float acc = (r == c) ? 1.f : 0.f;
        for (int j = c; j < r; ++j) acc -= D[r][j] * T[j][c];
        T[r][c] = (r >= c) ? acc / D[r][r] : 0.f;
    }
    __syncthreads();
    for (int idx = c; idx < 4096; idx += 64) {
        int r = idx >> 6, j = idx & 63;
        W[(size_t)(b*64+r)*512 + b*64 + j] = T[r][j];
    }
}

// Generic small square GEMM: C = sign * A(HxH) * B(HxH), batched over blockIdx.z
__global__ void __launch_bounds__(256) gemm_sq(const float* __restrict__ A, int lda, long asz,
        const float* __restrict__ B, int ldb, long bsz,
        float* __restrict__ C, int ldc, long csz, int H, float sign) {
    const float* Ab = A + (long)blockIdx.z * asz;
    const float* Bb = B + (long)blockIdx.z * bsz;
    float* Cb = C + (long)blockIdx.z * csz;
    const int r0 = blockIdx.y*64, c0 = blockIdx.x*64;
    __shared__ float As[32][65];
    __shared__ float Bs[32][65];
    const int tid = threadIdx.x;
    const int i0 = (tid & 15)*4, j0 = (tid >> 4)*4;
    float acc[4][4];
    #pragma unroll
    for (int i = 0; i < 4; ++i)
        #pragma unroll
        for (int j = 0; j < 4; ++j) acc[i][j] = 0.f;
    for (int kc = 0; kc < H; kc += 32) {
        __syncthreads();
        for (int idx = tid; idx < 2048; idx += 256) {   // As: k-fastest (coalesced rows of A)
            int k = idx & 31, x = idx >> 5;
            As[k][x] = Ab[(size_t)(r0+x)*lda + kc + k];
        }
        for (int idx = tid; idx < 2048; idx += 256) {   // Bs: x-fastest (coalesced rows of B)
            int x = idx & 63, k = idx >> 6;
            Bs[k][x] = Bb[(size_t)(kc+k)*ldb + c0 + x];
        }
        __syncthreads();
        #pragma unroll 8
        for (int k = 0; k < 32; ++k) {
            float a[4], b[4];
            *(float4*)a = *(const float4*)&As[k][i0];
            *(float4*)b = *(const float4*)&Bs[k][j0];
            #pragma unroll
            for (int i = 0; i < 4; ++i)
                #pragma unroll
                for (int j = 0; j < 4; ++j) acc[i][j] += a[i]*b[j];
        }
    }
    #pragma unroll
    for (int i = 0; i < 4; ++i) {
        float4 v = make_float4(sign*acc[i][0], sign*acc[i][1], sign*acc[i][2], sign*acc[i][3]);
        *(float4*)&Cb[(size_t)(r0+i0+i)*ldc + c0 + j0] = v;
    }
}

// z[0:512] = W*B ; z[512:1024] = W*1   (one wave per row)
__global__ void __launch_bounds__(256) gemv_W(const float* __restrict__ W,
        const float* __restrict__ Bvec, float* __restrict__ z) {
    int row = blockIdx.x*4 + (threadIdx.x >> 6);
    int lane = threadIdx.x & 63;
    const float* wr = W + (size_t)row*512;
    float a1 = 0.f, a2 = 0.f;
    for (int c = lane; c < 512; c += 64) {
        float w = wr[c];
        a1 += w * Bvec[c];
        a2 += w;
    }
    #pragma unroll
    for (int off = 32; off; off >>= 1) {
        a1 += __shfl_down(a1, off);
        a2 += __shfl_down(a2, off);
    }
    if (lane == 0) { z[row] = a1; z[512+row] = a2; }
}

// x[c] = sum_i W[i][c]*z[i] ; x[512+c] likewise for z2   (8 blocks x 64 cols)
__global__ void __launch_bounds__(64) gemv_WT(const float* __restrict__ W,
        const float* __restrict__ z, float* __restrict__ x) {
    int c = blockIdx.x*64 + threadIdx.x;
    float a1 = 0.f, a2 = 0.f;
    for (int i = 0; i < 512; ++i) {
        float w = W[(size_t)i*512 + c];
        a1 += w * z[i];
        a2 += w * z[512+i];
    }
    x[c] = a1;
    x[512+c] = a2;
}

// q = x1 - x2*(x2^T B)/(sum x2)
__global__ void __launch_bounds__(512) combine(const float* __restrict__ x,
        const float* __restrict__ Bvec, float* __restrict__ out) {
    __shared__ float rnum[8], rden[8];
    const int tid = threadIdx.x;
    float x1 = x[tid], x2 = x[512+tid], b = Bvec[tid];
    float pnum = x2*b, pden = x2;
    #pragma unroll
    for (int off = 32; off; off >>= 1) {
        pnum += __shfl_down(pnum, off);
        pden += __shfl_down(pden, off);
    }
    if ((tid & 63) == 0) { rnum[tid >> 6] = pnum; rden[tid >> 6] = pden; }
    __syncthreads();
    if (tid == 0) {
        float sn = 0.f, sd = 0.f;
        #pragma unroll
        for (int i = 0; i < 8; ++i) { sn += rnum[i]; sd += rden[i]; }
        rnum[0] = sn; rden[0] = sd;
    }
    __syncthreads();
    out[tid] = x1 - x2 * (rnum[0] / rden[0]);
}

extern "C" void kernel_launch(void* const* d_in, const int* in_sizes, int n_in,
                              void* d_out, int out_size, void* d_ws, size_t ws_size,
                              hipStream_t stream) {
    (void)in_sizes; (void)n_in; (void)out_size;
    const float* pos  = (const float*)d_in[0];
    const float* q    = (const float*)d_in[1];
    const float* cell = (const float*)d_in[2];
    float* out = (float*)d_out;
    char* ws = (char*)d_ws;
    size_t off = 0;
    auto alloc = [&](size_t bytes) -> void* {
        void* p = (void*)(ws + off);
        off = (off + bytes + 255) & ~(size_t)255;
        return p;
    };
    float4* kdata = (float4*)alloc((size_t)KPAD*16);
    float4* uq    = (float4*)alloc((size_t)N_ATOMS*16);
    float*  Scw   = (float*)alloc((size_t)KPAD*4);
    float*  Ssw   = (float*)alloc((size_t)KPAD*4);
    float*  Bvec  = (float*)alloc(512*4);
    float*  Amat  = (float*)alloc((size_t)512*512*4);
    float*  Wmat  = (float*)alloc((size_t)512*512*4);
    float*  M1    = (float*)alloc((size_t)256*256*4);
    float*  zvec  = (float*)alloc(1024*4);
    float*  xvec  = (float*)alloc(1024*4);
    // split-K factor (KSL must be divisible by 32 -> KS in divisors below)
    static const int ksopts[] = {48, 36, 24, 18, 12, 9, 8, 6, 4, 3, 2, 1};
    int KS = 1;
    for (int ci = 0; ci < 12; ++ci) {
        size_t need = (size_t)10 * ksopts[ci] * 16384 * 4;
        if (off + need <= ws_size) { KS = ksopts[ci]; break; }
    }
    float* partial = (float*)alloc((size_t)10*KS*16384*4);
    int KSL = KPAD / KS;

    k_setup<<<dim3(KPAD/256), dim3(256), 0, stream>>>(cell, kdata);
    atoms_prep<<<dim3(N_ATOMS/256), dim3(256), 0, stream>>>(pos, q, cell, uq, out);
    structf<<<dim3(KPAD/256), dim3(256), 0, stream>>>(kdata, uq, Scw, Ssw);
    field_metal<<<dim3(64), dim3(512), 0, stream>>>(kdata, uq, Scw, Ssw, cell, Bvec);
    syrk_tiles<<<dim3(10*KS), dim3(256), 0, stream>>>(kdata, uq, partial, KS, KSL);
    reduceA<<<dim3(1024), dim3(256), 0, stream>>>(partial, Amat, cell, KS);
    hipMemsetAsync(Wmat, 0, (size_t)512*512*4, stream);
    for (int p = 0; p < 8; ++p) {
        chol_panel<<<dim3(1), dim3(512 - 64*p), 0, stream>>>(Amat, p);
        int T = 7 - p;
        if (T > 0) chol_trail<<<dim3(T*(T+1)/2), dim3(256), 0, stream>>>(Amat, p);
    }
    inv_diag<<<dim3(8), dim3(64), 0, stream>>>(Amat, Wmat);
    // W = L^-1 via recursive doubling: W21 = -W22 * L21 * W11
    for (int lvl = 0; lvl < 3; ++lvl) {
        int H = 64 << lvl;           // 64, 128, 256
        int pairs = 4 >> lvl;        // 4, 2, 1
        long stp = (long)2*H*513;    // offset between pair group origins in 512x512
        // M1 = L21 * W11
        gemm_sq<<<dim3(H/64, H/64, pairs), dim3(256), 0, stream>>>(
            Amat + (size_t)H*512, 512, stp,
            Wmat, 512, stp,
            M1, H, (long)H*H, H, 1.0f);
        // W21 = -W22 * M1
        gemm_sq<<<dim3(H/64, H/64, pairs), dim3(256), 0, stream>>>(
            Wmat + (size_t)H*512 + H, 512, stp,
            M1, H, (long)H*H,
            Wmat + (size_t)H*512, 512, stp, H, -1.0f);
    }
    gemv_W<<<dim3(128), dim3(256), 0, stream>>>(Wmat, Bvec, zvec);
    gemv_WT<<<dim3(8), dim3(64), 0, stream>>>(Wmat, zvec, xvec);
    combine<<<dim3(1), dim3(512), 0, stream>>>(xvec, Bvec, out);
}

// Round 4
// 896.466 us; speedup vs baseline: 1.0428x; 1.0428x over previous
//
#include <hip/hip_runtime.h>
#include <hip/hip_cooperative_groups.h>
#include <math.h>

namespace cg = cooperative_groups;

#define N_ATOMS 2048
#define NM      512
#define KHALF   9040          // half k-grid (k=0 excluded; pairs folded into wk^2=2*kfac)
#define KPAD    9216          // padded, wk=0 on pads
#define TWO_PI  6.2831853071795864769f
#define SIGMA   0.5540037f
#define FOUR_PI 12.566370614359172954f

struct MWArgs {
    const float* pos; const float* qv; const float* cell;
    float* out;
    float4* kdata; float4* uq; float* Scw; float* Ssw; float* Bvec;
    float* Amat; float* Lmat; float* LmatT; float* Dinvs; float* partial;
    int SL;
};

__device__ inline void inv3x3(const float* __restrict__ c, float inv[3][3], float& det) {
    float a00=c[0],a01=c[1],a02=c[2],a10=c[3],a11=c[4],a12=c[5],a20=c[6],a21=c[7],a22=c[8];
    float c00 =  a11*a22 - a12*a21;
    float c01 = -(a10*a22 - a12*a20);
    float c02 =  a10*a21 - a11*a20;
    det = a00*c00 + a01*c01 + a02*c02;
    float id = 1.0f/det;
    inv[0][0] = c00*id;
    inv[0][1] = -(a01*a22 - a02*a21)*id;
    inv[0][2] =  (a01*a12 - a02*a11)*id;
    inv[1][0] = c01*id;
    inv[1][1] =  (a00*a22 - a02*a20)*id;
    inv[1][2] = -(a00*a12 - a02*a10)*id;
    inv[2][0] = c02*id;
    inv[2][1] = -(a00*a21 - a01*a20)*id;
    inv[2][2] =  (a00*a11 - a01*a10)*id;
}

// ---------------- regular kernel 1: k-grid + atom prep ----------------
__global__ void prep(const float* __restrict__ pos, const float* __restrict__ qv,
                     const float* __restrict__ cell, float4* __restrict__ kdata,
                     float4* __restrict__ uq, float* __restrict__ out) {
    const int bb = blockIdx.x, tid = threadIdx.x;
    if (bb < 36) {
        int t = bb*256 + tid;
        float gx=0.f, gy=0.f, gz=0.f, wk=0.f;
        if (t < KHALF) {
            int iz = t % 41; int rem = t / 41; int iy = rem % 21; int ix = rem / 21;
            gx = (float)(ix - 10); gy = (float)(iy - 10); gz = (float)(iz - 20);
            float inv[3][3], det;
            inv3x3(cell, inv, det);
            float kx = TWO_PI*(gx*inv[0][0] + gy*inv[0][1] + gz*inv[0][2]);
            float ky = TWO_PI*(gx*inv[1][0] + gy*inv[1][1] + gz*inv[1][2]);
            float kz = TWO_PI*(gx*inv[2][0] + gy*inv[2][1] + gz*inv[2][2]);
            float k2 = kx*kx + ky*ky + kz*kz;
            float kfac = __expf(-0.5f*SIGMA*SIGMA*k2) / k2;
            wk = sqrtf(2.0f*kfac);
        }
        kdata[t] = make_float4(gx, gy, gz, wk);
    } else {
        int i = (bb-36)*256 + tid;
        float inv[3][3], det;
        inv3x3(cell, inv, det);
        float x = pos[3*i], y = pos[3*i+1], z = pos[3*i+2];
        float u = x*inv[0][0] + y*inv[1][0] + z*inv[2][0];
        float v = x*inv[0][1] + y*inv[1][1] + z*inv[2][1];
        float w = x*inv[0][2] + y*inv[1][2] + z*inv[2][2];
        float qi = qv[i];
        uq[i] = make_float4(u, v, w, qi);
        if (i >= NM) out[i] = qi;
        if (i == 0) { out[N_ATOMS] = 0.f; out[N_ATOMS+1] = 0.f; }
    }
}

// ---------------- regular kernel 2: split-K SYRK (R2-proven) ----------------
__global__ void __launch_bounds__(256, 2) syrk_tiles(const float4* __restrict__ kdata,
        const float4* __restrict__ uq, float* __restrict__ partial, int SL, int KSL) {
    int s = blockIdx.x % SL;
    int t = blockIdx.x / SL;
    int rt = 0;
    while ((rt+1)*(rt+2)/2 <= t) ++rt;
    int ct = t - rt*(rt+1)/2;
    const int row0 = rt << 7, c0 = ct << 7;
    __shared__ float crT[32][128];
    __shared__ float srT[32][128];
    __shared__ float ccT[32][128];
    __shared__ float scT[32][128];
    const int tid = threadIdx.x;
    const int i0 = (tid & 15) << 3;
    const int j0 = (tid >> 4) << 3;
    float acc[8][8];
    #pragma unroll
    for (int i = 0; i < 8; ++i)
        #pragma unroll
        for (int j = 0; j < 8; ++j) acc[i][j] = 0.f;
    const int k0 = s * KSL;
    const int nch = KSL >> 5;
    for (int ch = 0; ch < nch; ++ch) {
        int kc = k0 + (ch << 5);
        __syncthreads();
        #pragma unroll
        for (int w = 0; w < 16; ++w) {
            int job = tid + (w << 8);
            int kk = job >> 7, a = job & 127;
            float4 kd = kdata[kc + kk];
            float4 at = uq[row0 + a];
            float ph = TWO_PI*(kd.x*at.x + kd.y*at.y + kd.z*at.z);
            float sn, cs;
            __sincosf(ph, &sn, &cs);
            crT[kk][a] = kd.w * cs;
            srT[kk][a] = kd.w * sn;
        }
        #pragma unroll
        for (int w = 0; w < 16; ++w) {
            int job = tid + (w << 8);
            int kk = job >> 7, a = job & 127;
            float4 kd = kdata[kc + kk];
            float4 at = uq[c0 + a];
            float ph = TWO_PI*(kd.x*at.x + kd.y*at.y + kd.z*at.z);
            float sn, cs;
            __sincosf(ph, &sn, &cs);
            ccT[kk][a] = kd.w * cs;
            scT[kk][a] = kd.w * sn;
        }
        __syncthreads();
        #pragma unroll 4
        for (int kk = 0; kk < 32; ++kk) {
            float cr[8], sr[8], cc[8], sv[8];
            *(float4*)&cr[0] = *(const float4*)&crT[kk][i0];
            *(float4*)&cr[4] = *(const float4*)&crT[kk][i0+4];
            *(float4*)&sr[0] = *(const float4*)&srT[kk][i0];
            *(float4*)&sr[4] = *(const float4*)&srT[kk][i0+4];
            *(float4*)&cc[0] = *(const float4*)&ccT[kk][j0];
            *(float4*)&cc[4] = *(const float4*)&ccT[kk][j0+4];
            *(float4*)&sv[0] = *(const float4*)&scT[kk][j0];
            *(float4*)&sv[4] = *(const float4*)&scT[kk][j0+4];
            #pragma unroll
            for (int i = 0; i < 8; ++i)
                #pragma unroll
                for (int j = 0; j < 8; ++j)
                    acc[i][j] += cr[i]*cc[j] + sr[i]*sv[j];
        }
    }
    float* P = partial + ((size_t)blockIdx.x << 14);
    #pragma unroll
    for (int i = 0; i < 8; ++i) {
        *(float4*)&P[(i0+i)*128 + j0]     = make_float4(acc[i][0], acc[i][1], acc[i][2], acc[i][3]);
        *(float4*)&P[(i0+i)*128 + j0 + 4] = make_float4(acc[i][4], acc[i][5], acc[i][6], acc[i][7]);
    }
}

// Factor 64x64 SPD tile D (LDS, ld=68) in place -> L, write chol block pd to Lmat/LmatT,
// compute T = L^{-1} (in-block recursive doubling), write dense to Dinvs[pd].
__device__ void diag_finish(float* D, float* T, float* M, int tid, int pd,
                            float* Lmat, float* LmatT, float* Dinvs) {
    for (int jb = 0; jb < 64; jb += 8) {
        if (tid < 64) {
            int r = tid;
            #pragma unroll
            for (int jj = 0; jj < 8; ++jj) {
                int j = jb + jj;
                float dj = D[j*68+j];       // all lanes read before lane j overwrites
                float piv = sqrtf(dj);
                float invp = 1.0f / piv;
                if (r == j) D[j*68+j] = piv;
                if (r > j) {
                    float lr = D[r*68+j] * invp;
                    D[r*68+j] = lr;          // lockstep: stores precede subsequent loads
                    #pragma unroll
                    for (int c2 = jj+1; c2 < 8; ++c2)
                        D[r*68+jb+c2] -= lr * D[(jb+c2)*68+j];
                }
            }
        }
        __syncthreads();
        if (jb + 8 < 64) {
            int rr = jb + 8 + (tid >> 2);
            int s4 = tid & 3;
            if (rr < 64) {
                for (int c = jb + 8 + s4; c <= rr; c += 4) {
                    float acc = 0.f;
                    #pragma unroll
                    for (int jj = 0; jj < 8; ++jj) acc += D[rr*68+jb+jj]*D[c*68+jb+jj];
                    D[rr*68+c] -= acc;
                }
            }
            __syncthreads();
        }
    }
    const int p64 = pd*64;
    for (int idx = tid; idx < 4096; idx += 256) {
        int r = idx >> 6, c = idx & 63;
        Lmat[(size_t)(p64+r)*512 + p64 + c] = (c <= r) ? D[r*68+c] : 0.f;
    }
    for (int idx = tid; idx < 4096; idx += 256) {
        int c = idx >> 6, r = idx & 63;
        LmatT[(size_t)(p64+c)*512 + p64 + r] = (c <= r) ? D[r*68+c] : 0.f;
    }
    for (int idx = tid; idx < 64*68; idx += 256) T[idx] = 0.f;
    __syncthreads();
    if (tid < 64) {
        int s = tid >> 3, c = tid & 7, o = s*8;
        float x[8];
        #pragma unroll
        for (int r = 0; r < 8; ++r) {
            float acc = (r == c) ? 1.0f : 0.0f;
            #pragma unroll
            for (int j = 0; j < 8; ++j)
                if (j < r) acc -= D[(o+r)*68 + o + j] * x[j];
            x[r] = (r >= c) ? acc / D[(o+r)*68 + o + r] : 0.0f;
        }
        #pragma unroll
        for (int r = 0; r < 8; ++r)
            if (r >= c) T[(o+r)*68 + o + c] = x[r];
    }
    __syncthreads();
    #pragma unroll
    for (int lvl = 0; lvl < 3; ++lvl) {
        int h = 8 << lvl, pairs = 4 >> lvl, hh = h*h;
        for (int e = tid; e < pairs*hh; e += 256) {   // M = L21 * W11
            int pr = e / hh, rem = e - pr*hh, r2 = rem / h, c2 = rem - (rem/h)*h;
            int o = pr*2*h;
            float acc = 0.f;
            for (int j2 = c2; j2 < h; ++j2)
                acc += D[(o+h+r2)*68 + o + j2] * T[(o+j2)*68 + o + c2];
            M[e] = acc;
        }
        __syncthreads();
        for (int e = tid; e < pairs*hh; e += 256) {   // W21 = -W22 * M
            int pr = e / hh, rem = e - pr*hh, r2 = rem / h, c2 = rem - (rem/h)*h;
            int o = pr*2*h;
            float acc = 0.f;
            for (int j2 = 0; j2 <= r2; ++j2)
                acc += T[(o+h+r2)*68 + o+h + j2] * M[pr*hh + j2*h + c2];
            T[(o+h+r2)*68 + o + c2] = -acc;
        }
        __syncthreads();
    }
    for (int idx = tid; idx < 4096; idx += 256) {
        int r = idx >> 6, c = idx & 63;
        Dinvs[pd*4096 + idx] = (c <= r) ? T[r*68+c] : 0.f;
    }
}

// ---------------- cooperative kernel: everything after the SYRK partials ----------------
__global__ void __launch_bounds__(256) mw_rest(MWArgs a) {
    __shared__ float smem[15360];   // 60 KB
    cg::grid_group grid = cg::this_grid();
    const int b = blockIdx.x, tid = threadIdx.x, G = gridDim.x;

    // P2: structure factors + reduceA
    for (int ch = b; ch < 36; ch += G) {
        int t = ch*256 + tid;
        float4 kd = a.kdata[t];
        float sc = 0.f, ss = 0.f;
        for (int j = NM; j < N_ATOMS; ++j) {
            float4 at = a.uq[j];
            float ph = TWO_PI*(kd.x*at.x + kd.y*at.y + kd.z*at.z);
            float s, c; __sincosf(ph, &s, &c);
            sc += at.w * c;
            ss += at.w * s;
        }
        float kfac2 = kd.w * kd.w;
        a.Scw[t] = kfac2 * sc;
        a.Ssw[t] = kfac2 * ss;
    }
    {
        float inv[3][3], det;
        inv3x3(a.cell, inv, det);
        const float scal = FOUR_PI / fabsf(det);
        const int SL = a.SL;
        for (int idx = b*256 + tid; idx < 512*512; idx += G*256) {
            int i = idx >> 9, j = idx & 511;
            if (i < j) continue;
            int rt2 = i >> 7, ct2 = j >> 7;
            int t2 = rt2*(rt2+1)/2 + ct2;
            const float* p = a.partial + ((size_t)(t2*SL) << 14) + ((i & 127) << 7) + (j & 127);
            float sum = 0.f;
            for (int s = 0; s < SL; ++s) sum += p[(size_t)s << 14];
            float v = scal * sum;
            a.Amat[(size_t)i*512 + j] = v;
            a.Amat[(size_t)j*512 + i] = v;
        }
    }
    grid.sync();

    // P3: field on metal atoms + diag0 factor/inverse
    for (int ch = b; ch < 128; ch += G) {
        int atom = ch*4 + (tid >> 6);
        int lane = tid & 63;
        float4 at = a.uq[atom];
        float acc = 0.f;
        for (int k = lane; k < KPAD; k += 64) {
            float4 kd = a.kdata[k];
            float ph = TWO_PI*(kd.x*at.x + kd.y*at.y + kd.z*at.z);
            float s, c; __sincosf(ph, &s, &c);
            acc += c*a.Scw[k] + s*a.Ssw[k];
        }
        #pragma unroll
        for (int off = 32; off; off >>= 1) acc += __shfl_down(acc, off);
        if (lane == 0) {
            float inv[3][3], det;
            inv3x3(a.cell, inv, det);
            a.Bvec[atom] = -(FOUR_PI / fabsf(det)) * acc;
        }
    }
    if (b == 0) {
        float* D = smem; float* T = smem + 4352; float* M = smem + 8704;
        __syncthreads();
        for (int idx = tid; idx < 4096; idx += 256) {
            int r = idx >> 6, c = idx & 63;
            D[r*68+c] = a.Amat[(size_t)r*512 + c];
        }
        __syncthreads();
        diag_finish(D, T, M, tid, 0, a.Lmat, a.LmatT, a.Dinvs);
    }
    grid.sync();

    // Cholesky steps p=0..6 (fused TRSM + trailing SYRK + next pivot factor/inverse)
    for (int p = 0; p <= 6; ++p) {
        const int T7 = 7 - p, ntile = T7*(T7+1)/2;
        const int nmine = (b < ntile) ? ((ntile - 1 - b)/G + 1) : 0;
        for (int m = nmine - 1; m >= 0; --m) {   // reverse so tile 0 (designated) runs last
            const int tt = b + m*G;
            int rt = 0; while ((rt+1)*(rt+2)/2 <= tt) ++rt;
            const int ct = tt - rt*(rt+1)/2;
            const int R = p + 1 + rt, C = p + 1 + ct;
            float* ArT = smem;            // [64][68]
            float* DvT = smem + 4352;     // [64][68]
            float* LrT = smem + 8704;     // [64][68]
            float* LcT = smem + 13056;    // [64][36]
            __syncthreads();              // guard LDS reuse across tiles
            for (int idx = tid; idx < 4096; idx += 256) {
                int j = idx >> 6, d = idx & 63;
                DvT[d*68 + j] = a.Dinvs[p*4096 + j*64 + d];
            }
            for (int idx = tid; idx < 4096; idx += 256) {
                int i = idx >> 6, k = idx & 63;
                ArT[k*68 + i] = a.Amat[(size_t)(R*64 + i)*512 + p*64 + k];
            }
            __syncthreads();
            const int i0 = (tid & 15)*4, j0 = (tid >> 4)*4;
            float lr[4][4];
            #pragma unroll
            for (int ii = 0; ii < 4; ++ii)
                #pragma unroll
                for (int jj = 0; jj < 4; ++jj) lr[ii][jj] = 0.f;
            for (int k = 0; k < 64; ++k) {     // Lr = A21r * Dinv^T
                float4 av = *(float4*)&ArT[k*68 + i0];
                float4 dv = *(float4*)&DvT[k*68 + j0];
                lr[0][0] += av.x*dv.x; lr[0][1] += av.x*dv.y; lr[0][2] += av.x*dv.z; lr[0][3] += av.x*dv.w;
                lr[1][0] += av.y*dv.x; lr[1][1] += av.y*dv.y; lr[1][2] += av.y*dv.z; lr[1][3] += av.y*dv.w;
                lr[2][0] += av.z*dv.x; lr[2][1] += av.z*dv.y; lr[2][2] += av.z*dv.z; lr[2][3] += av.z*dv.w;
                lr[3][0] += av.w*dv.x; lr[3][1] += av.w*dv.y; lr[3][2] += av.w*dv.z; lr[3][3] += av.w*dv.w;
            }
            #pragma unroll
            for (int ii = 0; ii < 4; ++ii)
                #pragma unroll
                for (int jj = 0; jj < 4; ++jj)
                    LrT[(j0+jj)*68 + i0+ii] = lr[ii][jj];
            __syncthreads();
            if (C == p + 1) {   // write panel column of L (+ transpose)
                for (int idx = tid; idx < 4096; idx += 256) {
                    int i2 = idx >> 6, c2 = idx & 63;
                    a.Lmat[(size_t)(R*64+i2)*512 + p*64 + c2] = LrT[c2*68 + i2];
                }
                for (int idx = tid; idx < 4096; idx += 256) {
                    int c2 = idx >> 6, i2 = idx & 63;
                    a.LmatT[(size_t)(p*64+c2)*512 + R*64 + i2] = LrT[c2*68 + i2];
                }
            }
            if (R == C) {
                float up[4][4];
                #pragma unroll
                for (int ii = 0; ii < 4; ++ii)
                    #pragma unroll
                    for (int jj = 0; jj < 4; ++jj) up[ii][jj] = 0.f;
                for (int k = 0; k < 64; ++k) {
                    float4 av = *(float4*)&LrT[k*68 + i0];
                    float4 bv = *(float4*)&LrT[k*68 + j0];
                    up[0][0] += av.x*bv.x; up[0][1] += av.x*bv.y; up[0][2] += av.x*bv.z; up[0][3] += av.x*bv.w;
                    up[1][0] += av.y*bv.x; up[1][1] += av.y*bv.y; up[1][2] += av.y*bv.z; up[1][3] += av.y*bv.w;
                    up[2][0] += av.z*bv.x; up[2][1] += av.z*bv.y; up[2][2] += av.z*bv.z; up[2][3] += av.z*bv.w;
                    up[3][0] += av.w*bv.x; up[3][1] += av.w*bv.y; up[3][2] += av.w*bv.z; up[3][3] += av.w*bv.w;
                }
                float vals[4][4];
                #pragma unroll
                for (int ii = 0; ii < 4; ++ii)
                    #pragma unroll
                    for (int jj = 0; jj < 4; ++jj) {
                        size_t gix = (size_t)(R*64+i0+ii)*512 + C*64 + j0 + jj;
                        float v = a.Amat[gix] - up[ii][jj];
                        a.Amat[gix] = v;
                        vals[ii][jj] = v;
                    }
                if (tt == 0) {   // designated: factor + invert next pivot
                    float* D = smem; float* T = smem + 4352; float* M = smem + 8704;
                    __syncthreads();
                    #pragma unroll
                    for (int ii = 0; ii < 4; ++ii)
                        #pragma unroll
                        for (int jj = 0; jj < 4; ++jj)
                            D[(i0+ii)*68 + j0+jj] = vals[ii][jj];
                    __syncthreads();
                    diag_finish(D, T, M, tid, p+1, a.Lmat, a.LmatT, a.Dinvs);
                }
            } else {
                for (int idx = tid; idx < 4096; idx += 256) {  // restage: A21c into ArT
                    int i2 = idx >> 6, k = idx & 63;
                    ArT[k*68 + i2] = a.Amat[(size_t)(C*64 + i2)*512 + p*64 + k];
                }
                __syncthreads();
                const int c0l = (tid & 15)*4, jr0 = (tid >> 4)*2;
                #pragma unroll
                for (int hh = 0; hh < 2; ++hh) {
                    float lc[4][2];
                    #pragma unroll
                    for (int cc = 0; cc < 4; ++cc) { lc[cc][0] = 0.f; lc[cc][1] = 0.f; }
                    for (int d = 0; d < 64; ++d) {
                        float4 dv = *(float4*)&DvT[d*68 + c0l];
                        float2 av = *(float2*)&ArT[d*68 + hh*32 + jr0];
                        lc[0][0] += dv.x*av.x; lc[0][1] += dv.x*av.y;
                        lc[1][0] += dv.y*av.x; lc[1][1] += dv.y*av.y;
                        lc[2][0] += dv.z*av.x; lc[2][1] += dv.z*av.y;
                        lc[3][0] += dv.w*av.x; lc[3][1] += dv.w*av.y;
                    }
                    __syncthreads();
                    #pragma unroll
                    for (int cc = 0; cc < 4; ++cc) {
                        LcT[(c0l+cc)*36 + jr0]     = lc[cc][0];
                        LcT[(c0l+cc)*36 + jr0 + 1] = lc[cc][1];
                    }
                    __syncthreads();
                    float up[4][2];
                    #pragma unroll
                    for (int ii = 0; ii < 4; ++ii) { up[ii][0] = 0.f; up[ii][1] = 0.f; }
                    for (int c2 = 0; c2 < 64; ++c2) {
                        float4 lv = *(float4*)&LrT[c2*68 + i0];
                        float2 cv = *(float2*)&LcT[c2*36 + jr0];
                        up[0][0] += lv.x*cv.x; up[0][1] += lv.x*cv.y;
                        up[1][0] += lv.y*cv.x; up[1][1] += lv.y*cv.y;
                        up[2][0] += lv.z*cv.x; up[2][1] += lv.z*cv.y;
                        up[3][0] += lv.w*cv.x; up[3][1] += lv.w*cv.y;
                    }
                    #pragma unroll
                    for (int ii = 0; ii < 4; ++ii)
                        #pragma unroll
                        for (int jr = 0; jr < 2; ++jr) {
                            size_t gix = (size_t)(R*64+i0+ii)*512 + C*64 + hh*32 + jr0 + jr;
                            a.Amat[gix] -= up[ii][jr];
                        }
                }
            }
        }
        grid.sync();
    }

    // Solve: L z = [B,1]; L^T x = z; combine; out[0:512]
    if (b == 0) {
        float* rb  = smem;
        float* ro  = smem + 512;
        float* xb  = smem + 1024;
        float* xo  = smem + 1536;
        float* bvs = smem + 2048;
        float* red = smem + 2560;
        __syncthreads();
        for (int i = tid; i < 512; i += 256) {
            float bv = a.Bvec[i];
            bvs[i] = bv; rb[i] = bv; ro[i] = 1.0f;
        }
        __syncthreads();
        for (int k = 0; k < 8; ++k) {          // forward
            if (tid < 64) {
                const float* Dk = a.Dinvs + k*4096 + tid*64;
                float s1 = 0.f, s2 = 0.f;
                for (int c4 = 0; c4 < 16; ++c4) {
                    float4 w = *(const float4*)&Dk[c4*4];
                    int cb = 64*k + c4*4;
                    s1 += w.x*rb[cb] + w.y*rb[cb+1] + w.z*rb[cb+2] + w.w*rb[cb+3];
                    s2 += w.x*ro[cb] + w.y*ro[cb+1] + w.z*ro[cb+2] + w.w*ro[cb+3];
                }
                rb[64*k+tid] = s1; ro[64*k+tid] = s2;   // wave-lockstep: loads precede stores
            }
            __syncthreads();
            for (int mm = 64*(k+1) + tid; mm < 512; mm += 256) {
                const float* Lr = a.Lmat + (size_t)mm*512 + 64*k;
                float s1 = 0.f, s2 = 0.f;
                for (int c4 = 0; c4 < 16; ++c4) {
                    float4 l = *(const float4*)&Lr[c4*4];
                    int cb = 64*k + c4*4;
                    s1 += l.x*rb[cb] + l.y*rb[cb+1] + l.z*rb[cb+2] + l.w*rb[cb+3];
                    s2 += l.x*ro[cb] + l.y*ro[cb+1] + l.z*ro[cb+2] + l.w*ro[cb+3];
                }
                rb[mm] -= s1; ro[mm] -= s2;
            }
            __syncthreads();
        }
        for (int k = 7; k >= 0; --k) {         // backward
            if (tid < 64) {
                const float* D0 = a.Dinvs + k*4096;
                float s1 = 0.f, s2 = 0.f;
                for (int c = 0; c < 64; ++c) {
                    float w = D0[c*64 + tid];
                    s1 += w*rb[64*k+c]; s2 += w*ro[64*k+c];
                }
                xb[64*k+tid] = s1; xo[64*k+tid] = s2;
            }
            __syncthreads();
            for (int mm = tid; mm < 64*k; mm += 256) {
                const float* Ur = a.LmatT + (size_t)mm*512 + 64*k;
                float s1 = 0.f, s2 = 0.f;
                for (int c4 = 0; c4 < 16; ++c4) {
                    float4 u = *(const float4*)&Ur[c4*4];
                    int cb = 64*k + c4*4;
                    s1 += u.x*xb[cb] + u.y*xb[cb+1] + u.z*xb[cb+2] + u.w*xb[cb+3];
                    s2 += u.x*xo[cb] + u.y*xo[cb+1] + u.z*xo[cb+2] + u.w*xo[cb+3];
                }
                rb[mm] -= s1; ro[mm] -= s2;
            }
            __syncthreads();
        }
        float pn = 0.f, pd = 0.f;
        for (int i = tid; i < 512; i += 256) { pn += xo[i]*bvs[i]; pd += xo[i]; }
        #pragma unroll
        for (int off = 32; off; off >>= 1) { pn += __shfl_down(pn, off); pd += __shfl_down(pd, off); }
        if ((tid & 63) == 0) { red[tid >> 6] = pn; red[4 + (tid >> 6)] = pd; }
        __syncthreads();
        if (tid == 0) {
            float sn = red[0]+red[1]+red[2]+red[3];
            float sd = red[4]+red[5]+red[6]+red[7];
            red[8] = sn / sd;
        }
        __syncthreads();
        float ratio = red[8];
        for (int i = tid; i < 512; i += 256) a.out[i] = xb[i] - xo[i]*ratio;
    }
}

extern "C" void kernel_launch(void* const* d_in, const int* in_sizes, int n_in,
                              void* d_out, int out_size, void* d_ws, size_t ws_size,
                              hipStream_t stream) {
    (void)in_sizes; (void)n_in; (void)out_size;
    char* ws = (char*)d_ws;
    size_t off = 0;
    auto alloc = [&](size_t bytes) -> void* {
        void* p = (void*)(ws + off);
        off = (off + bytes + 255) & ~(size_t)255;
        return p;
    };
    MWArgs args;
    args.pos  = (const float*)d_in[0];
    args.qv   = (const float*)d_in[1];
    args.cell = (const float*)d_in[2];
    args.out  = (float*)d_out;
    args.kdata = (float4*)alloc((size_t)KPAD*16);
    args.uq    = (float4*)alloc((size_t)N_ATOMS*16);
    args.Scw   = (float*)alloc((size_t)KPAD*4);
    args.Ssw   = (float*)alloc((size_t)KPAD*4);
    args.Bvec  = (float*)alloc(512*4);
    args.Amat  = (float*)alloc((size_t)512*512*4);
    args.Lmat  = (float*)alloc((size_t)512*512*4);
    args.LmatT = (float*)alloc((size_t)512*512*4);
    args.Dinvs = (float*)alloc((size_t)8*4096*4);
    // SL must divide 288 (so KSL = KPAD/SL is a multiple of 32)
    static const int slopts[9] = {48, 36, 24, 16, 12, 8, 4, 2, 1};
    int SL = 1;
    for (int ci = 0; ci < 9; ++ci) {
        size_t need = (size_t)10 * slopts[ci] * 16384 * 4;
        if (off + need <= ws_size) { SL = slopts[ci]; break; }
    }
    args.partial = (float*)alloc((size_t)10*SL*16384*4);
    args.SL = SL;
    const int KSL = KPAD / SL;

    prep<<<dim3(44), dim3(256), 0, stream>>>(args.pos, args.qv, args.cell,
                                             args.kdata, args.uq, args.out);
    syrk_tiles<<<dim3(10*SL), dim3(256), 0, stream>>>(args.kdata, args.uq,
                                                      args.partial, SL, KSL);
    void* kp[] = { (void*)&args };
    hipLaunchCooperativeKernel((const void*)mw_rest, dim3(128), dim3(256), kp, 0, stream);
}